// Round 7
// baseline (180.436 us; speedup 1.0000x reference)
//
#include <hip/hip_runtime.h>

typedef unsigned short ushort_t;
typedef unsigned int   uint_t;

typedef __attribute__((ext_vector_type(8))) short  short8;   // 8 bf16 in 4 VGPRs
typedef __attribute__((ext_vector_type(4))) float  float4v;  // MFMA 16x16 acc

#define BB    8
#define CC    256
#define HH    64
#define WW2   64
#define NPIX  4096   // H*W
#define MPOS  1024   // (H/2)*(W/2)
#define ICH   64
#define NBLK  512    // fused grid size (256 CU x 2 blocks/CU, co-resident)

__device__ __forceinline__ ushort_t f2bf(float f) {
  uint_t i = __float_as_uint(f);
  uint_t r = (i + 0x7FFFu + ((i >> 16) & 1u)) >> 16;  // RNE
  return (ushort_t)r;
}
__device__ __forceinline__ ushort_t f2bf_rna(float f) {   // cheap round-half-away
  return (ushort_t)((__float_as_uint(f) + 0x8000u) >> 16);
}
__device__ __forceinline__ uint_t pack2(float a, float b) {
  return (uint_t)f2bf(a) | ((uint_t)f2bf(b) << 16);
}

// async global->LDS, 16B per lane; LDS dest = wave-uniform base + lane*16
__device__ __forceinline__ void gl2lds16(const ushort_t* g, ushort_t* l) {
  __builtin_amdgcn_global_load_lds(
      (const __attribute__((address_space(1))) void*)g,
      (__attribute__((address_space(3))) void*)l, 16, 0, 0);
}

// manual device-scope grid barrier (all NBLK blocks co-resident by
// construction: launch_bounds(256,2), grid = 2 x 256 CU). Release fence ->
// device-scope atomic arrive -> bounded spin -> acquire fence.
__device__ __forceinline__ void grid_barrier(uint_t* bar) {
  __syncthreads();
  if (threadIdx.x == 0) {
    __threadfence();                       // release: flush our global writes
    atomicAdd(bar, 1u);                    // device-scope
    int guard = 0;
    while (atomicAdd(bar, 0u) < NBLK && guard < (1 << 20)) {
      __builtin_amdgcn_s_sleep(8);
      ++guard;
    }
    __threadfence();                       // acquire
  }
  __syncthreads();
}

// ---------------------------------------------------------------------------
// K0: weight prep into coalesced-fragment layouts (unchanged):
//   wA2 [32 kblk][192 o][8 k], Wbf2 [8 icblk][256 o][8 ic], biasAll [192] f32
// ---------------------------------------------------------------------------
__global__ __launch_bounds__(256) void prep_kernel(
    const float* __restrict__ theta_w, const float* __restrict__ phi_w,
    const float* __restrict__ g_w, const float* __restrict__ W_w,
    const float* __restrict__ theta_b, const float* __restrict__ phi_b,
    const float* __restrict__ g_b,
    ushort_t* __restrict__ wA2, ushort_t* __restrict__ Wbf2,
    float* __restrict__ biasAll) {
  int i = blockIdx.x * 256 + threadIdx.x;
  if (i < 49152) {         // theta|phi|g -> wA2
    float v = (i < 16384) ? theta_w[i]
            : (i < 32768) ? phi_w[i - 16384]
                          : g_w[i - 32768];
    int o = i >> 8, c = i & 255;
    wA2[(c >> 3) * 1536 + o * 8 + (c & 7)] = f2bf(v);
  } else if (i < 65536) {  // W_w -> Wbf2
    int j = i - 49152;
    int o = j >> 6, ic = j & 63;
    Wbf2[(ic >> 3) * 2048 + o * 8 + (ic & 7)] = f2bf(W_w[j]);
  } else if (i < 65600)    biasAll[i - 65536] = theta_b[i - 65536];
  else if (i < 65664)      biasAll[i - 65536] = phi_b[i - 65600];
  else if (i < 65728)      biasAll[i - 65536] = g_b[i - 65664];
}

// ---------------------------------------------------------------------------
// FUSED qkv + attention kernel: phase1 = r4 qkv body | manual grid barrier |
// phase2 = r3 attn body. Plain (graph-capturable) launch; 512 blocks x 256
// threads, exactly 2 blocks/CU. LDS unioned: phase1 32KB x-tile, phase2
// 41KB Ks|Vs|Ps.
// ---------------------------------------------------------------------------
__global__ __launch_bounds__(256, 2) void fused_qkv_attn(
    const float* __restrict__ x, const ushort_t* __restrict__ wA2,
    const float* __restrict__ biasAll, const ushort_t* __restrict__ Wbf2,
    const float* __restrict__ W_b,
    ushort_t* __restrict__ qbuf, ushort_t* __restrict__ kTbuf,
    ushort_t* __restrict__ vTbuf, uint_t* __restrict__ bar,
    float* __restrict__ out) {
  __shared__ __align__(16) ushort_t SH[20992];   // 41984 B
  int tid = threadIdx.x;
  int wave = tid >> 6, lane = tid & 63;
  int quad = lane >> 4, col = lane & 15;
  int b = blockIdx.x & 7;                        // batch pinned per blockIdx%8

  // ===== phase 1: q/k/v conv GEMM + 2x2 maxpool (r4 body) =====
  {
    uint4* Bs16 = (uint4*)SH;          // 64 pixels x 256 ch bf16 = 32KB
    int t = blockIdx.x >> 3;
    int rj = t >> 1, h = t & 1;

    {
      int pg = tid & 15, cb = tid >> 4;
      int prow = pg >> 3;
      int pcol = (pg * 4) & 31;
      const float* xsrc = x + (size_t)b * (CC * NPIX) +
                          (size_t)(2 * rj + prow) * WW2 + h * 32 + pcol;
      float4 v[16];
#pragma unroll
      for (int c = 0; c < 16; ++c)
        v[c] = *(const float4*)&xsrc[(size_t)(cb * 16 + c) * NPIX];
#pragma unroll
      for (int j = 0; j < 4; ++j) {
        int pos = pg * 4 + j;
        uint4 w0, w1;
        w0.x = pack2(v[0][j],  v[1][j]);
        w0.y = pack2(v[2][j],  v[3][j]);
        w0.z = pack2(v[4][j],  v[5][j]);
        w0.w = pack2(v[6][j],  v[7][j]);
        w1.x = pack2(v[8][j],  v[9][j]);
        w1.y = pack2(v[10][j], v[11][j]);
        w1.z = pack2(v[12][j], v[13][j]);
        w1.w = pack2(v[14][j], v[15][j]);
        int jb0 = cb * 2, jb1 = cb * 2 + 1;
        Bs16[pos * 32 + (jb0 & ~7) + ((jb0 & 7) ^ (pos & 7))] = w0;
        Bs16[pos * 32 + (jb1 & ~7) + ((jb1 & 7) ^ (pos & 7))] = w1;
      }
    }
    __syncthreads();

    float4v acc[3][4];
#pragma unroll
    for (int ot = 0; ot < 3; ++ot) {
      int ob = wave * 48 + ot * 16 + quad * 4;
      float4v bv;
#pragma unroll
      for (int r = 0; r < 4; ++r) bv[r] = biasAll[ob + r];
#pragma unroll
      for (int s = 0; s < 4; ++s) acc[ot][s] = bv;
    }

    const uint4* wA16 = (const uint4*)wA2;
#pragma unroll
    for (int ks = 0; ks < 8; ++ks) {
      int kblk = ks * 4 + quad;
      short8 aw[3];
#pragma unroll
      for (int ot = 0; ot < 3; ++ot) {
        uint4 a = wA16[kblk * 192 + wave * 48 + ot * 16 + col];
        aw[ot] = *(const short8*)&a;
      }
#pragma unroll
      for (int s = 0; s < 4; ++s) {
        int lp = s * 16 + col;
        uint4 braw = Bs16[lp * 32 + (kblk & ~7) + ((kblk & 7) ^ (lp & 7))];
        short8 bx = *(const short8*)&braw;
#pragma unroll
        for (int ot = 0; ot < 3; ++ot)
          acc[ot][s] = __builtin_amdgcn_mfma_f32_16x16x32_bf16(aw[ot], bx, acc[ot][s], 0, 0, 0);
      }
    }

#pragma unroll
    for (int ot = 0; ot < 3; ++ot) {
      int ob = wave * 48 + ot * 16;
      if (ob < 64) {  // theta -> qbuf[b][n][o]
#pragma unroll
        for (int s = 0; s < 4; ++s) {
          int n = (2 * rj + (s >> 1)) * WW2 + h * 32 + (s & 1) * 16 + col;
          uint2 u;
          u.x = pack2(acc[ot][s][0], acc[ot][s][1]);
          u.y = pack2(acc[ot][s][2], acc[ot][s][3]);
          *(uint2*)&qbuf[((size_t)(b * NPIX + n)) * ICH + ob + quad * 4] = u;
        }
      } else if (ob < 128) {  // phi -> pool -> kTbuf[b][m][ic]
#pragma unroll
        for (int s = 0; s < 2; ++s) {
          float4v pm;
#pragma unroll
          for (int r = 0; r < 4; ++r) {
            float v = fmaxf(acc[ot][s][r], acc[ot][s + 2][r]);
            pm[r] = fmaxf(v, __shfl_xor(v, 1));
          }
          if ((lane & 1) == 0) {
            int m = rj * 32 + h * 16 + s * 8 + (col >> 1);
            uint2 u;
            u.x = pack2(pm[0], pm[1]);
            u.y = pack2(pm[2], pm[3]);
            *(uint2*)&kTbuf[((size_t)(b * MPOS + m)) * ICH + (ob - 64) + quad * 4] = u;
          }
        }
      } else {  // g -> pool -> vTbuf[b][ic][m]
#pragma unroll
        for (int s = 0; s < 2; ++s) {
          float4v pm;
#pragma unroll
          for (int r = 0; r < 4; ++r) {
            float v = fmaxf(acc[ot][s][r], acc[ot][s + 2][r]);
            pm[r] = fmaxf(v, __shfl_xor(v, 1));
          }
          if ((lane & 1) == 0) {
            int m = rj * 32 + h * 16 + s * 8 + (col >> 1);
#pragma unroll
            for (int r = 0; r < 4; ++r)
              vTbuf[((size_t)(b * ICH + (ob - 128) + quad * 4 + r)) * MPOS + m] = f2bf(pm[r]);
          }
        }
      }
    }
  }

  grid_barrier(bar);

  // ===== phase 2: attention + output conv + residual (r3 body) =====
  {
    ushort_t* Ks0 = SH;                 // [2][64*64]
    ushort_t* Vs0 = SH + 8192;          // [2][64*64]
    ushort_t* Ps  = SH + 16384;         // [4][16*72]
    int qt = blockIdx.x >> 3;

    ushort_t* Psw = Ps + wave * (16 * 72);

    const ushort_t* qrow = qbuf + ((size_t)(b * NPIX + qt * 64 + wave * 16 + col)) * ICH;
    short8 aQ0 = *(const short8*)&qrow[quad * 8];
    short8 aQ1 = *(const short8*)&qrow[32 + quad * 8];

    int srow = tid >> 3, sblk = tid & 7;
    int swz  = (sblk ^ (srow & 7)) * 8;
    const ushort_t* kg = kTbuf + (size_t)b * MPOS * ICH;
    const ushort_t* vg = vTbuf + (size_t)b * ICH * MPOS;
    const ushort_t* kg0 = kg + srow * ICH + swz;
    const ushort_t* kg1 = kg + (32 + srow) * ICH + swz;
    const ushort_t* vg0 = vg + (size_t)srow * MPOS + swz;
    const ushort_t* vg1 = vg + (size_t)(32 + srow) * MPOS + swz;

#define STAGE(bufi, kt)                                               \
    do {                                                              \
      gl2lds16(kg0 + (kt) * 4096, Ks0 + (bufi) * 4096 + wave * 512);  \
      gl2lds16(kg1 + (kt) * 4096, Ks0 + (bufi) * 4096 + 2048 + wave * 512); \
      gl2lds16(vg0 + (kt) * 64,   Vs0 + (bufi) * 4096 + wave * 512);  \
      gl2lds16(vg1 + (kt) * 64,   Vs0 + (bufi) * 4096 + 2048 + wave * 512); \
    } while (0)

    STAGE(0, 0);
    __syncthreads();

    const float4v zero4 = {0.f, 0.f, 0.f, 0.f};
    float l_lane = 0.f;                  // denominator partial for q = col
    float4v o_acc[4];
#pragma unroll
    for (int t = 0; t < 4; ++t) o_acc[t] = zero4;

    for (int kt = 0; kt < 16; ++kt) {
      int buf = kt & 1;
      if (kt < 15) STAGE(buf ^ 1, kt + 1);   // async DMA under this iteration

      // S^T = K . Q^T : s_acc[t][r] = S[key=t*16+quad*4+r][q=col]
      float4v s_acc[4];
      __builtin_amdgcn_s_setprio(1);
#pragma unroll
      for (int t = 0; t < 4; ++t) {
        float4v s = zero4;
        short8 ak0 = *(const short8*)&Ks0[buf * 4096 + (t * 16 + col) * 64 + ((quad ^ (col & 7)) * 8)];
        s = __builtin_amdgcn_mfma_f32_16x16x32_bf16(ak0, aQ0, s, 0, 0, 0);
        short8 ak1 = *(const short8*)&Ks0[buf * 4096 + (t * 16 + col) * 64 + (((4 + quad) ^ (col & 7)) * 8)];
        s = __builtin_amdgcn_mfma_f32_16x16x32_bf16(ak1, aQ1, s, 0, 0, 0);
        s_acc[t] = s;
      }
      __builtin_amdgcn_s_setprio(0);

      // P^T tile: exp, pack key-pairs, 8B stores into PT[q=col][key]
#pragma unroll
      for (int t = 0; t < 4; ++t) {
        float p0 = __expf(s_acc[t][0]);
        float p1 = __expf(s_acc[t][1]);
        float p2 = __expf(s_acc[t][2]);
        float p3 = __expf(s_acc[t][3]);
        l_lane += (p0 + p1) + (p2 + p3);
        uint2 u;
        u.x = (uint_t)f2bf_rna(p0) | ((uint_t)f2bf_rna(p1) << 16);
        u.y = (uint_t)f2bf_rna(p2) | ((uint_t)f2bf_rna(p3) << 16);
        *(uint2*)&Psw[col * 72 + t * 16 + quad * 4] = u;
      }

      // O += P . V
      __builtin_amdgcn_s_setprio(1);
#pragma unroll
      for (int kk = 0; kk < 2; ++kk) {
        short8 ap = *(const short8*)&Psw[col * 72 + kk * 32 + quad * 8];
#pragma unroll
        for (int t = 0; t < 4; ++t) {
          short8 bv = *(const short8*)&Vs0[buf * 4096 + (t * 16 + col) * 64 + (((kk * 4 + quad) ^ (col & 7)) * 8)];
          o_acc[t] = __builtin_amdgcn_mfma_f32_16x16x32_bf16(ap, bv, o_acc[t], 0, 0, 0);
        }
      }
      __builtin_amdgcn_s_setprio(0);

      __syncthreads();   // drains DMA + all waves done with buf
    }
#undef STAGE

    // softmax denominator: sum across the 4 quads holding q = col
    l_lane += __shfl_xor(l_lane, 16);
    l_lane += __shfl_xor(l_lane, 32);
    float invl = 1.0f / l_lane;

    // normalize O, write attended rows [q][ic] into wave-private Ps rows
#pragma unroll
    for (int r = 0; r < 4; ++r) {
      float iv = __shfl(invl, (lane & 48) | (quad * 4 + r));
      int prow = (quad * 4 + r) * 72;
#pragma unroll
      for (int t = 0; t < 4; ++t)
        Psw[prow + t * 16 + col] = f2bf(o_acc[t][r] * iv);
    }

    // fused output conv: D[p=16 per wave][o=256] + residual
    short8 ap0 = *(const short8*)&Psw[col * 72 + quad * 8];
    short8 ap1 = *(const short8*)&Psw[col * 72 + 32 + quad * 8];
    const uint4* W16 = (const uint4*)Wbf2;
    int pbase = qt * 64 + wave * 16 + quad * 4;
#pragma unroll
    for (int ot = 0; ot < 16; ++ot) {
      float bvv = W_b[ot * 16 + col];
      float4v c = {bvv, bvv, bvv, bvv};
      uint4 w0 = W16[quad * 256 + ot * 16 + col];
      uint4 w1 = W16[(4 + quad) * 256 + ot * 16 + col];
      c = __builtin_amdgcn_mfma_f32_16x16x32_bf16(ap0, *(const short8*)&w0, c, 0, 0, 0);
      c = __builtin_amdgcn_mfma_f32_16x16x32_bf16(ap1, *(const short8*)&w1, c, 0, 0, 0);
      size_t idx = ((size_t)(b * CC + ot * 16 + col)) * NPIX + pbase;
      float4 xv = *(const float4*)&x[idx];
      float4 ov;
      ov.x = c[0] + xv.x;
      ov.y = c[1] + xv.y;
      ov.z = c[2] + xv.z;
      ov.w = c[3] + xv.w;
      *(float4*)&out[idx] = ov;
    }
  }
}

// ---------------------------------------------------------------------------
extern "C" void kernel_launch(void* const* d_in, const int* in_sizes, int n_in,
                              void* d_out, int out_size, void* d_ws, size_t ws_size,
                              hipStream_t stream) {
  const float* x       = (const float*)d_in[0];
  const float* g_w     = (const float*)d_in[1];
  const float* g_b     = (const float*)d_in[2];
  const float* theta_w = (const float*)d_in[3];
  const float* theta_b = (const float*)d_in[4];
  const float* phi_w   = (const float*)d_in[5];
  const float* phi_b   = (const float*)d_in[6];
  const float* W_w     = (const float*)d_in[7];
  const float* W_b     = (const float*)d_in[8];
  (void)in_sizes; (void)n_in; (void)out_size; (void)ws_size;

  char* ws = (char*)d_ws;
  ushort_t* wA2     = (ushort_t*)(ws + 0);         // 96KB bf16 [32][192][8]
  ushort_t* Wbf2    = (ushort_t*)(ws + 98304);     // 32KB bf16 [8][256][8]
  float*    biasAll = (float*)(ws + 131072);       // 768B
  uint_t*   bar     = (uint_t*)(ws + 196608);      // grid-barrier counter
  ushort_t* qbuf    = (ushort_t*)(ws + 262144);    // 4MB bf16 [8][4096][64]
  ushort_t* kTbuf   = (ushort_t*)(ws + 4456448);   // 1MB bf16 [8][1024][64]
  ushort_t* vTbuf   = (ushort_t*)(ws + 5505024);   // 1MB bf16 [8][64][1024]
  float* out = (float*)d_out;

  hipMemsetAsync(bar, 0, 256, stream);   // zero barrier counter (capturable)
  prep_kernel<<<257, 256, 0, stream>>>(theta_w, phi_w, g_w, W_w,
                                       theta_b, phi_b, g_b,
                                       wA2, Wbf2, biasAll);
  fused_qkv_attn<<<512, 256, 0, stream>>>(x, wA2, biasAll, Wbf2, W_b,
                                          qbuf, kTbuf, vTbuf, bar, out);
}

// Round 8
// 127.377 us; speedup vs baseline: 1.4166x; 1.4166x over previous
//
#include <hip/hip_runtime.h>

typedef unsigned short ushort_t;
typedef unsigned int   uint_t;

typedef __attribute__((ext_vector_type(8))) short  short8;   // 8 bf16 in 4 VGPRs
typedef __attribute__((ext_vector_type(4))) float  float4v;  // MFMA 16x16 acc

#define BB    8
#define CC    256
#define HH    64
#define WW2   64
#define NPIX  4096   // H*W
#define MPOS  1024   // (H/2)*(W/2)
#define ICH   64

__device__ __forceinline__ ushort_t f2bf(float f) {
  uint_t i = __float_as_uint(f);
  uint_t r = (i + 0x7FFFu + ((i >> 16) & 1u)) >> 16;  // RNE
  return (ushort_t)r;
}
__device__ __forceinline__ ushort_t f2bf_rna(float f) {   // cheap round-half-away
  return (ushort_t)((__float_as_uint(f) + 0x8000u) >> 16);
}
__device__ __forceinline__ uint_t pack2(float a, float b) {
  return (uint_t)f2bf(a) | ((uint_t)f2bf(b) << 16);
}

// async global->LDS, 16B per lane; LDS dest = wave-uniform base + lane*16
__device__ __forceinline__ void gl2lds16(const ushort_t* g, ushort_t* l) {
  __builtin_amdgcn_global_load_lds(
      (const __attribute__((address_space(1))) void*)g,
      (__attribute__((address_space(3))) void*)l, 16, 0, 0);
}

// ---------------------------------------------------------------------------
// K0: weight prep into coalesced-fragment layouts (r4 verbatim):
//   wA2 [32 kblk][192 o][8 k], Wbf2 [8 icblk][256 o][8 ic], biasAll [192] f32
// ---------------------------------------------------------------------------
__global__ __launch_bounds__(256) void prep_kernel(
    const float* __restrict__ theta_w, const float* __restrict__ phi_w,
    const float* __restrict__ g_w, const float* __restrict__ W_w,
    const float* __restrict__ theta_b, const float* __restrict__ phi_b,
    const float* __restrict__ g_b,
    ushort_t* __restrict__ wA2, ushort_t* __restrict__ Wbf2,
    float* __restrict__ biasAll) {
  int i = blockIdx.x * 256 + threadIdx.x;
  if (i < 49152) {         // theta|phi|g -> wA2
    float v = (i < 16384) ? theta_w[i]
            : (i < 32768) ? phi_w[i - 16384]
                          : g_w[i - 32768];
    int o = i >> 8, c = i & 255;
    wA2[(c >> 3) * 1536 + o * 8 + (c & 7)] = f2bf(v);
  } else if (i < 65536) {  // W_w -> Wbf2
    int j = i - 49152;
    int o = j >> 6, ic = j & 63;
    Wbf2[(ic >> 3) * 2048 + o * 8 + (ic & 7)] = f2bf(W_w[j]);
  } else if (i < 65600)    biasAll[i - 65536] = theta_b[i - 65536];
  else if (i < 65664)      biasAll[i - 65536] = phi_b[i - 65600];
  else if (i < 65728)      biasAll[i - 65536] = g_b[i - 65664];
}

// ---------------------------------------------------------------------------
// K1: q/k/v conv GEMM + 2x2 maxpool (r4 verbatim).
// ---------------------------------------------------------------------------
__global__ __launch_bounds__(256, 2) void qkv_kernel(
    const float* __restrict__ x, const ushort_t* __restrict__ wA2,
    const float* __restrict__ biasAll,
    ushort_t* __restrict__ qbuf, ushort_t* __restrict__ kTbuf,
    ushort_t* __restrict__ vTbuf) {
  __shared__ __align__(16) ushort_t Bsu[64 * 256];
  uint4* Bs16 = (uint4*)Bsu;
  int tid = threadIdx.x;
  int wave = tid >> 6, lane = tid & 63;
  int quad = lane >> 4, col = lane & 15;
  int b = blockIdx.x & 7, t = blockIdx.x >> 3;   // batch -> XCD pinned
  int rj = t >> 1, h = t & 1;

  {
    int pg = tid & 15, cb = tid >> 4;
    int prow = pg >> 3;
    int pcol = (pg * 4) & 31;
    const float* xsrc = x + (size_t)b * (CC * NPIX) +
                        (size_t)(2 * rj + prow) * WW2 + h * 32 + pcol;
    float4 v[16];
#pragma unroll
    for (int c = 0; c < 16; ++c)
      v[c] = *(const float4*)&xsrc[(size_t)(cb * 16 + c) * NPIX];
#pragma unroll
    for (int j = 0; j < 4; ++j) {
      int pos = pg * 4 + j;
      uint4 w0, w1;
      w0.x = pack2(v[0][j],  v[1][j]);
      w0.y = pack2(v[2][j],  v[3][j]);
      w0.z = pack2(v[4][j],  v[5][j]);
      w0.w = pack2(v[6][j],  v[7][j]);
      w1.x = pack2(v[8][j],  v[9][j]);
      w1.y = pack2(v[10][j], v[11][j]);
      w1.z = pack2(v[12][j], v[13][j]);
      w1.w = pack2(v[14][j], v[15][j]);
      int jb0 = cb * 2, jb1 = cb * 2 + 1;
      Bs16[pos * 32 + (jb0 & ~7) + ((jb0 & 7) ^ (pos & 7))] = w0;
      Bs16[pos * 32 + (jb1 & ~7) + ((jb1 & 7) ^ (pos & 7))] = w1;
    }
  }
  __syncthreads();

  float4v acc[3][4];
#pragma unroll
  for (int ot = 0; ot < 3; ++ot) {
    int ob = wave * 48 + ot * 16 + quad * 4;
    float4v bv;
#pragma unroll
    for (int r = 0; r < 4; ++r) bv[r] = biasAll[ob + r];
#pragma unroll
    for (int s = 0; s < 4; ++s) acc[ot][s] = bv;
  }

  const uint4* wA16 = (const uint4*)wA2;
#pragma unroll
  for (int ks = 0; ks < 8; ++ks) {
    int kblk = ks * 4 + quad;
    short8 aw[3];
#pragma unroll
    for (int ot = 0; ot < 3; ++ot) {
      uint4 a = wA16[kblk * 192 + wave * 48 + ot * 16 + col];
      aw[ot] = *(const short8*)&a;
    }
#pragma unroll
    for (int s = 0; s < 4; ++s) {
      int lp = s * 16 + col;
      uint4 braw = Bs16[lp * 32 + (kblk & ~7) + ((kblk & 7) ^ (lp & 7))];
      short8 bx = *(const short8*)&braw;
#pragma unroll
      for (int ot = 0; ot < 3; ++ot)
        acc[ot][s] = __builtin_amdgcn_mfma_f32_16x16x32_bf16(aw[ot], bx, acc[ot][s], 0, 0, 0);
    }
  }

#pragma unroll
  for (int ot = 0; ot < 3; ++ot) {
    int ob = wave * 48 + ot * 16;
    if (ob < 64) {  // theta -> qbuf[b][n][o]
#pragma unroll
      for (int s = 0; s < 4; ++s) {
        int n = (2 * rj + (s >> 1)) * WW2 + h * 32 + (s & 1) * 16 + col;
        uint2 u;
        u.x = pack2(acc[ot][s][0], acc[ot][s][1]);
        u.y = pack2(acc[ot][s][2], acc[ot][s][3]);
        *(uint2*)&qbuf[((size_t)(b * NPIX + n)) * ICH + ob + quad * 4] = u;
      }
    } else if (ob < 128) {  // phi -> pool -> kTbuf[b][m][ic]
#pragma unroll
      for (int s = 0; s < 2; ++s) {
        float4v pm;
#pragma unroll
        for (int r = 0; r < 4; ++r) {
          float v = fmaxf(acc[ot][s][r], acc[ot][s + 2][r]);
          pm[r] = fmaxf(v, __shfl_xor(v, 1));
        }
        if ((lane & 1) == 0) {
          int m = rj * 32 + h * 16 + s * 8 + (col >> 1);
          uint2 u;
          u.x = pack2(pm[0], pm[1]);
          u.y = pack2(pm[2], pm[3]);
          *(uint2*)&kTbuf[((size_t)(b * MPOS + m)) * ICH + (ob - 64) + quad * 4] = u;
        }
      }
    } else {  // g -> pool -> vTbuf[b][ic][m]
#pragma unroll
      for (int s = 0; s < 2; ++s) {
        float4v pm;
#pragma unroll
        for (int r = 0; r < 4; ++r) {
          float v = fmaxf(acc[ot][s][r], acc[ot][s + 2][r]);
          pm[r] = fmaxf(v, __shfl_xor(v, 1));
        }
        if ((lane & 1) == 0) {
          int m = rj * 32 + h * 16 + s * 8 + (col >> 1);
#pragma unroll
          for (int r = 0; r < 4; ++r)
            vTbuf[((size_t)(b * ICH + (ob - 128) + quad * 4 + r)) * MPOS + m] = f2bf(pm[r]);
        }
      }
    }
  }
}

// ---------------------------------------------------------------------------
// K2: attention + output conv + residual, COARSE-GRAINED:
//   - 512-thread blocks (8 waves x 16 queries = 128 q/block), grid 256.
//   - KVBLK=256 keys per interval: 4 iterations, 8 barriers total (vs 16).
//   - K [256][64] and V [64][256] single-buffered in LDS (32+32 KB), staged
//     via pre-swizzled-source global_load_lds; barrier-free 32-key chunk
//     pipeline inside each interval: QK(2 sub-tiles) -> exp -> tiny
//     wave-private P chunk [16][40] -> PV, so chunk c+1's QK hides chunk c's
//     P LDS round-trip. o_acc / l accumulation order identical to r4.
//   - epilogue reuses freed K space for attended rows (stride 72, as r3).
// Dynamic LDS 75776 B.
// ---------------------------------------------------------------------------
__global__ __launch_bounds__(512) void attn_out_kernel(
    const ushort_t* __restrict__ qbuf, const ushort_t* __restrict__ kTbuf,
    const ushort_t* __restrict__ vTbuf, const ushort_t* __restrict__ Wbf2,
    const float* __restrict__ W_b, const float* __restrict__ x,
    float* __restrict__ out) {
  extern __shared__ __align__(16) ushort_t SH[];
  ushort_t* Ks = SH;                 // [256 m][64 ic], 8-blk XOR(row&7) image
  ushort_t* Vs = SH + 16384;         // [64 ic][256 m], XOR within 128B groups
  ushort_t* Ps = SH + 32768;         // 8 waves x [16 q][40] chunk buffers
  int tid  = threadIdx.x;
  int wave = tid >> 6, lane = tid & 63;
  int quad = lane >> 4, col = lane & 15;
  int b = blockIdx.x & 7, qt = blockIdx.x >> 3;   // batch -> XCD pinned

  ushort_t* Psw = Ps + wave * (16 * 40);          // wave-private [16][40]

  // Q fragments (B-operand of swapped QK)
  const ushort_t* qrow = qbuf + ((size_t)(b * NPIX + qt * 128 + wave * 16 + col)) * ICH;
  short8 aQ0 = *(const short8*)&qrow[quad * 8];
  short8 aQ1 = *(const short8*)&qrow[32 + quad * 8];

  // ---- staging addresses (pre-swizzled global source, linear LDS dest) ----
  // K: per wave-instr g: rows [g*64 + wave*8, +8), 8x16B blocks per row.
  int srow8 = lane >> 3, sblk = lane & 7;
  const ushort_t* kgL = kTbuf + (size_t)b * MPOS * ICH +
                        (wave * 8 + srow8) * ICH + ((sblk ^ srow8) * 8);
  // V: per wave-instr g: 2 ic-rows (wave*8 + g*2 + (lane>>5)), 32x16B blocks.
  const ushort_t* vgL[4];
  int vblk = lane & 31;
#pragma unroll
  for (int g = 0; g < 4; ++g) {
    int vic = wave * 8 + g * 2 + (lane >> 5);
    int swz = ((vblk & ~7) | ((vblk & 7) ^ (vic & 7))) * 8;
    vgL[g] = vTbuf + (size_t)b * ICH * MPOS + (size_t)vic * MPOS + swz;
  }

#define STAGE(kt)                                                         \
  do {                                                                    \
    _Pragma("unroll")                                                     \
    for (int g = 0; g < 4; ++g)                                           \
      gl2lds16(kgL + ((kt) * 256 + g * 64) * ICH,                         \
               Ks + (g * 64 + wave * 8) * 64);                            \
    _Pragma("unroll")                                                     \
    for (int g = 0; g < 4; ++g)                                           \
      gl2lds16(vgL[g] + (kt) * 256, Vs + (wave * 8 + g * 2) * 256);       \
  } while (0)

  STAGE(0);
  __syncthreads();                       // drains DMA (vmcnt 0)

  const float4v zero4 = {0.f, 0.f, 0.f, 0.f};
  float l_lane = 0.f;                    // denominator partial for q = col
  float4v o_acc[4];
#pragma unroll
  for (int t = 0; t < 4; ++t) o_acc[t] = zero4;

  int kswz0 = (quad ^ (col & 7)) * 8;
  int kswz1 = ((4 + quad) ^ (col & 7)) * 8;

  for (int it = 0; it < 4; ++it) {
    // ---- 8 barrier-free 32-key chunks: QK -> exp -> P chunk -> PV ----
#pragma unroll
    for (int c = 0; c < 8; ++c) {
#pragma unroll
      for (int hh = 0; hh < 2; ++hh) {
        int tt = c * 2 + hh;
        // S^T sub-tile: s[r] = S[key=tt*16+quad*4+r][q=col]
        float4v s = zero4;
        short8 ak0 = *(const short8*)&Ks[(tt * 16 + col) * 64 + kswz0];
        s = __builtin_amdgcn_mfma_f32_16x16x32_bf16(ak0, aQ0, s, 0, 0, 0);
        short8 ak1 = *(const short8*)&Ks[(tt * 16 + col) * 64 + kswz1];
        s = __builtin_amdgcn_mfma_f32_16x16x32_bf16(ak1, aQ1, s, 0, 0, 0);
        float p0 = __expf(s[0]);
        float p1 = __expf(s[1]);
        float p2 = __expf(s[2]);
        float p3 = __expf(s[3]);
        l_lane += (p0 + p1) + (p2 + p3);
        uint2 u;
        u.x = (uint_t)f2bf_rna(p0) | ((uint_t)f2bf_rna(p1) << 16);
        u.y = (uint_t)f2bf_rna(p2) | ((uint_t)f2bf_rna(p3) << 16);
        *(uint2*)&Psw[col * 40 + hh * 16 + quad * 4] = u;
      }
      // PV for this 32-key chunk (same-wave P read, no barrier)
      short8 ap = *(const short8*)&Psw[col * 40 + quad * 8];
      int blk = c * 4 + quad;
#pragma unroll
      for (int t = 0; t < 4; ++t) {
        int rswz = ((blk & ~7) | ((blk & 7) ^ (col & 7))) * 8;
        short8 bv = *(const short8*)&Vs[(t * 16 + col) * 256 + rswz];
        o_acc[t] = __builtin_amdgcn_mfma_f32_16x16x32_bf16(ap, bv, o_acc[t], 0, 0, 0);
      }
    }
    __syncthreads();                     // all waves done reading K/V
    if (it < 3) {
      STAGE(it + 1);
      __syncthreads();                   // DMA drained, tiles visible
    }
  }
#undef STAGE

  // ---- softmax denominator: sum across the 4 quads holding q = col
  l_lane += __shfl_xor(l_lane, 16);
  l_lane += __shfl_xor(l_lane, 32);
  float invl = 1.0f / l_lane;

  // normalize O into attended rows [q][ic] in freed K space (wave-private)
  ushort_t* Att = Ks + wave * (16 * 72);
#pragma unroll
  for (int r = 0; r < 4; ++r) {
    float iv = __shfl(invl, (lane & 48) | (quad * 4 + r));
    int prow = (quad * 4 + r) * 72;
#pragma unroll
    for (int t = 0; t < 4; ++t)
      Att[prow + t * 16 + col] = f2bf(o_acc[t][r] * iv);
  }

  // ---- fused output conv: D[p=16 per wave][o=256] + residual
  short8 ap0 = *(const short8*)&Att[col * 72 + quad * 8];
  short8 ap1 = *(const short8*)&Att[col * 72 + 32 + quad * 8];
  const uint4* W16 = (const uint4*)Wbf2;
  int pbase = qt * 128 + wave * 16 + quad * 4;
#pragma unroll
  for (int ot = 0; ot < 16; ++ot) {
    float bvv = W_b[ot * 16 + col];
    float4v c = {bvv, bvv, bvv, bvv};
    uint4 w0 = W16[quad * 256 + ot * 16 + col];
    uint4 w1 = W16[(4 + quad) * 256 + ot * 16 + col];
    c = __builtin_amdgcn_mfma_f32_16x16x32_bf16(ap0, *(const short8*)&w0, c, 0, 0, 0);
    c = __builtin_amdgcn_mfma_f32_16x16x32_bf16(ap1, *(const short8*)&w1, c, 0, 0, 0);
    size_t idx = ((size_t)(b * CC + ot * 16 + col)) * NPIX + pbase;
    float4 xv = *(const float4*)&x[idx];
    float4 ov;
    ov.x = c[0] + xv.x;
    ov.y = c[1] + xv.y;
    ov.z = c[2] + xv.z;
    ov.w = c[3] + xv.w;
    *(float4*)&out[idx] = ov;
  }
}

// ---------------------------------------------------------------------------
extern "C" void kernel_launch(void* const* d_in, const int* in_sizes, int n_in,
                              void* d_out, int out_size, void* d_ws, size_t ws_size,
                              hipStream_t stream) {
  const float* x       = (const float*)d_in[0];
  const float* g_w     = (const float*)d_in[1];
  const float* g_b     = (const float*)d_in[2];
  const float* theta_w = (const float*)d_in[3];
  const float* theta_b = (const float*)d_in[4];
  const float* phi_w   = (const float*)d_in[5];
  const float* phi_b   = (const float*)d_in[6];
  const float* W_w     = (const float*)d_in[7];
  const float* W_b     = (const float*)d_in[8];
  (void)in_sizes; (void)n_in; (void)out_size; (void)ws_size;

  char* ws = (char*)d_ws;
  ushort_t* wA2     = (ushort_t*)(ws + 0);         // 96KB bf16 [32][192][8]
  ushort_t* Wbf2    = (ushort_t*)(ws + 98304);     // 32KB bf16 [8][256][8]
  float*    biasAll = (float*)(ws + 131072);       // 768B
  ushort_t* qbuf    = (ushort_t*)(ws + 262144);    // 4MB bf16 [8][4096][64]
  ushort_t* kTbuf   = (ushort_t*)(ws + 4456448);   // 1MB bf16 [8][1024][64]
  ushort_t* vTbuf   = (ushort_t*)(ws + 5505024);   // 1MB bf16 [8][64][1024]
  float* out = (float*)d_out;

  static bool attr_done = false;
  if (!attr_done) {
    hipFuncSetAttribute((const void*)attn_out_kernel,
                        hipFuncAttributeMaxDynamicSharedMemorySize, 75776);
    attr_done = true;
  }

  prep_kernel<<<257, 256, 0, stream>>>(theta_w, phi_w, g_w, W_w,
                                       theta_b, phi_b, g_b,
                                       wA2, Wbf2, biasAll);
  qkv_kernel<<<512, 256, 0, stream>>>(x, wA2, biasAll, qbuf, kTbuf, vTbuf);
  attn_out_kernel<<<256, 512, 75776, stream>>>(qbuf, kTbuf, vTbuf, Wbf2,
                                               W_b, x, out);
}